// Round 7
// baseline (106.746 us; speedup 1.0000x reference)
//
#include <hip/hip_runtime.h>

// Problem constants (fixed by the reference file)
#define NN 8192
#define DIN 256
#define DD 256
static const long long PP = (long long)NN * (NN - 1) / 2;   // 33,550,336
#define NSEG 16775168u   // P/2 (2-pair segments) = 2048 * 8191

typedef float __attribute__((ext_vector_type(4))) fx4;      // nontemporal-store-able

// LDS layout for M with per-32-row skew so the 8 dim-slices hit distinct banks
#define MS(j, c) Ms[(((j) << 2) + (c)) + ((((j) >> 5)) << 2)]

// ---------------------------------------------------------------------------
// Kernel 1: per-node projections, weight-combine fused (redundant per block).
//   M = W_enc @ [Wc_A | Wc_B]  (256x4),  off = b_enc @ [Wc_A|Wc_B] (+b_cls)
//   AB[n] = {A0,A1,B0,B1} = nodes[n] @ M + off
// 8 threads cooperate per node (32 dims each, shfl_xor reduce).
// grid = 256 blocks * 256 threads = 8 * 8192 nodes.
// ---------------------------------------------------------------------------
__global__ __launch_bounds__(256) void ab_kernel(
    const float* __restrict__ nodes,   // [8192][256]
    const float* __restrict__ W_enc,   // [256][256]
    const float* __restrict__ b_enc,   // [256]
    const float* __restrict__ W_cls,   // [512][2]
    const float* __restrict__ b_cls,   // [2]
    float4* __restrict__ AB)           // [8192] out
{
    __shared__ float wc[1024];         // W_cls staged: [512][2]
    __shared__ float Ms[1056];         // skewed M
    __shared__ float offs[4];
    const int tid = threadIdx.x;
    for (int i = tid; i < 1024; i += 256) wc[i] = W_cls[i];
    __syncthreads();

    // --- M row `tid` (redundant per block; W_enc is L2-resident) ---
    {
        float a0 = 0.f, a1 = 0.f, a2 = 0.f, a3 = 0.f;
        const float4* wrow = (const float4*)(W_enc + (long long)tid * DIN);
        #pragma unroll 8
        for (int i = 0; i < DIN / 4; ++i) {
            const float4 v = wrow[i];
            const int j = i * 4;
            a0 += v.x * wc[(j+0)*2+0] + v.y * wc[(j+1)*2+0]
                + v.z * wc[(j+2)*2+0] + v.w * wc[(j+3)*2+0];
            a1 += v.x * wc[(j+0)*2+1] + v.y * wc[(j+1)*2+1]
                + v.z * wc[(j+2)*2+1] + v.w * wc[(j+3)*2+1];
            a2 += v.x * wc[(DD+j+0)*2+0] + v.y * wc[(DD+j+1)*2+0]
                + v.z * wc[(DD+j+2)*2+0] + v.w * wc[(DD+j+3)*2+0];
            a3 += v.x * wc[(DD+j+0)*2+1] + v.y * wc[(DD+j+1)*2+1]
                + v.z * wc[(DD+j+2)*2+1] + v.w * wc[(DD+j+3)*2+1];
        }
        MS(tid, 0) = a0; MS(tid, 1) = a1; MS(tid, 2) = a2; MS(tid, 3) = a3;
    }

    // --- off (threads 0..3) ---
    if (tid < 4) {
        const int c = tid & 1;
        const int base = (tid < 2) ? 0 : DD;
        float o = 0.f;
        for (int j = 0; j < DIN; ++j) o += b_enc[j] * wc[(base + j) * 2 + c];
        if (tid < 2) o += b_cls[tid];     // fold b_cls into the A half
        offs[tid] = o;
    }
    __syncthreads();

    // --- cooperative per-node projection: 8 threads per node ---
    const int gid  = blockIdx.x * 256 + tid;
    const int n    = gid >> 3;            // 0..8191
    const int part = gid & 7;             // 32-dim slice
    float a0 = 0.f, a1 = 0.f, a2 = 0.f, a3 = 0.f;
    const float4* row = (const float4*)(nodes + (long long)n * DIN + part * 32);
    #pragma unroll
    for (int i = 0; i < 8; ++i) {
        const float4 v = row[i];
        const int j = part * 32 + i * 4;
        a0 += v.x * MS(j+0,0) + v.y * MS(j+1,0) + v.z * MS(j+2,0) + v.w * MS(j+3,0);
        a1 += v.x * MS(j+0,1) + v.y * MS(j+1,1) + v.z * MS(j+2,1) + v.w * MS(j+3,1);
        a2 += v.x * MS(j+0,2) + v.y * MS(j+1,2) + v.z * MS(j+2,2) + v.w * MS(j+3,2);
        a3 += v.x * MS(j+0,3) + v.y * MS(j+1,3) + v.z * MS(j+2,3) + v.w * MS(j+3,3);
    }
    #pragma unroll
    for (int d = 1; d < 8; d <<= 1) {
        a0 += __shfl_xor(a0, d);
        a1 += __shfl_xor(a1, d);
        a2 += __shfl_xor(a2, d);
        a3 += __shfl_xor(a3, d);
    }
    if (part == 0)
        AB[n] = make_float4(a0 + offs[0], a1 + offs[1], a2 + offs[2], a3 + offs[3]);
}

// ---------------------------------------------------------------------------
// Kernel 2: fill y.  2048 long-lived blocks; block b owns segments
// [b*8192, b*8192+8192) (segment = 2 pairs = one lane-contiguous fx4 store).
// 32 iterations, guarded tail (only last block masks).
// ---------------------------------------------------------------------------
__global__ __launch_bounds__(256) void fill_kernel(
    const float4* __restrict__ AB,     // [8192] {A0,A1,B0,B1}
    float* __restrict__ y)             // [P][2]
{
    const unsigned M = 2u * NN - 1u;                  // 16383
    const unsigned base = blockIdx.x * 8192u + threadIdx.x;

    #pragma unroll 4
    for (int it = 0; it < 32; ++it) {
        const unsigned g = base + (unsigned)it * 256u;
        if (g >= NSEG) break;
        const unsigned p0 = 2u * g;                   // < 2^26

        // invert p0 -> (s,t): s = floor((M - sqrt(M^2 - 8 p0))/2)
        const unsigned disc = M * M - 8u * p0;        // exact in uint32
        const float sq = sqrtf((float)disc);
        int s = (int)(((float)M - sq) * 0.5f);
        s = s < 0 ? 0 : (s > NN - 2 ? NN - 2 : s);
        unsigned rs = ((unsigned)s * (M - (unsigned)s)) >> 1;
        while (p0 < rs)                           { --s; rs -= (unsigned)(NN - 1 - s); }
        while (p0 >= rs + (unsigned)(NN - 1 - s)) { rs += (unsigned)(NN - 1 - s); ++s; }
        int t = (int)(p0 - rs) + s + 1;

        float4 a  = AB[s];
        float4 b0 = AB[t];
        const float o0 = a.x + b0.z, o1 = a.y + b0.w;
        if (++t == NN) { ++s; t = s + 1; a = AB[s]; }   // row crossing (rare)
        float4 b1 = AB[t];
        const float o2 = a.x + b1.z, o3 = a.y + b1.w;

        fx4 v = {o0, o1, o2, o3};
        __builtin_nontemporal_store(v, (fx4*)(y + 4u * g));
    }
}

// ---------------------------------------------------------------------------
// Kernel 3: zero yt.  2048 blocks * 256 threads * 16 fx4 = P floats exactly.
// Block owns a contiguous 256-KB chunk.
// ---------------------------------------------------------------------------
__global__ __launch_bounds__(256) void zero_kernel(float* __restrict__ yt)
{
    fx4* base = (fx4*)yt + blockIdx.x * 4096u + threadIdx.x;
    fx4 z = {0.f, 0.f, 0.f, 0.f};
    #pragma unroll
    for (int i = 0; i < 16; ++i)
        __builtin_nontemporal_store(z, base + i * 256);
}

// ---------------------------------------------------------------------------
// Kernel 4: scatter edge labels.  yt[pair_idx] = 1.0 for valid (u < v) edges.
// ---------------------------------------------------------------------------
__global__ __launch_bounds__(256) void edge_kernel(
    const int* __restrict__ edges,     // [2][E]
    float* __restrict__ yt,
    int E)
{
    const int e = blockIdx.x * 256 + threadIdx.x;
    if (e >= E) return;
    const int u = edges[e];
    const int v = edges[E + e];
    if (u < v) {
        const unsigned idx = (unsigned)u * (2u * NN - u - 1u) / 2u + (unsigned)(v - u - 1);
        yt[idx] = 1.0f;
    }
}

extern "C" void kernel_launch(void* const* d_in, const int* in_sizes, int n_in,
                              void* d_out, int out_size, void* d_ws, size_t ws_size,
                              hipStream_t stream) {
    const float* nodes = (const float*)d_in[0];
    const int*   edges = (const int*)d_in[1];
    const float* W_enc = (const float*)d_in[2];
    const float* b_enc = (const float*)d_in[3];
    const float* W_cls = (const float*)d_in[4];
    const float* b_cls = (const float*)d_in[5];
    const int E = in_sizes[1] / 2;

    float4* AB = (float4*)d_ws;                   // 8192 float4 (16B aligned)

    float* y  = (float*)d_out;                    // [P][2]
    float* yt = (float*)d_out + 2 * PP;           // [P]

    ab_kernel<<<256, 256, 0, stream>>>(nodes, W_enc, b_enc, W_cls, b_cls, AB);
    fill_kernel<<<2048, 256, 0, stream>>>(AB, y);
    zero_kernel<<<2048, 256, 0, stream>>>(yt);
    edge_kernel<<<(E + 255) / 256, 256, 0, stream>>>(edges, yt, E);
}

// Round 8
// 105.752 us; speedup vs baseline: 1.0094x; 1.0094x over previous
//
#include <hip/hip_runtime.h>

// Problem constants (fixed by the reference file)
#define NN 8192
#define DIN 256
#define DD 256
static const long long PP = (long long)NN * (NN - 1) / 2;   // 33,550,336

typedef float __attribute__((ext_vector_type(4))) fx4;      // nontemporal-store-able
typedef float __attribute__((ext_vector_type(2))) fx2;

// LDS layout for M with per-32-row skew so the 8 dim-slices hit distinct banks
#define MS(j, c) Ms[(((j) << 2) + (c)) + ((((j) >> 5)) << 2)]

// ---------------------------------------------------------------------------
// Kernel 1: per-node projections, weight-combine fused (redundant per block).
//   M = W_enc @ [Wc_A | Wc_B]  (256x4),  off = b_enc @ [Wc_A|Wc_B] (+b_cls)
//   Axy[n] = {A0,A1},  Bzw[n] = {B0,B1}   (SoA split for the fill gathers)
// 8 threads cooperate per node (32 dims each, shfl_xor reduce).
// grid = 256 blocks * 256 threads = 8 * 8192 nodes.
// ---------------------------------------------------------------------------
__global__ __launch_bounds__(256) void ab_kernel(
    const float* __restrict__ nodes,   // [8192][256]
    const float* __restrict__ W_enc,   // [256][256]
    const float* __restrict__ b_enc,   // [256]
    const float* __restrict__ W_cls,   // [512][2]
    const float* __restrict__ b_cls,   // [2]
    float2* __restrict__ Axy,          // [8192] out
    float2* __restrict__ Bzw)          // [8192] out
{
    __shared__ float wc[1024];         // W_cls staged: [512][2]
    __shared__ float Ms[1056];         // skewed M
    __shared__ float offs[4];
    const int tid = threadIdx.x;
    for (int i = tid; i < 1024; i += 256) wc[i] = W_cls[i];
    __syncthreads();

    // --- M row `tid` (redundant per block; W_enc is L2-resident) ---
    {
        float a0 = 0.f, a1 = 0.f, a2 = 0.f, a3 = 0.f;
        const float4* wrow = (const float4*)(W_enc + (long long)tid * DIN);
        #pragma unroll 8
        for (int i = 0; i < DIN / 4; ++i) {
            const float4 v = wrow[i];
            const int j = i * 4;
            a0 += v.x * wc[(j+0)*2+0] + v.y * wc[(j+1)*2+0]
                + v.z * wc[(j+2)*2+0] + v.w * wc[(j+3)*2+0];
            a1 += v.x * wc[(j+0)*2+1] + v.y * wc[(j+1)*2+1]
                + v.z * wc[(j+2)*2+1] + v.w * wc[(j+3)*2+1];
            a2 += v.x * wc[(DD+j+0)*2+0] + v.y * wc[(DD+j+1)*2+0]
                + v.z * wc[(DD+j+2)*2+0] + v.w * wc[(DD+j+3)*2+0];
            a3 += v.x * wc[(DD+j+0)*2+1] + v.y * wc[(DD+j+1)*2+1]
                + v.z * wc[(DD+j+2)*2+1] + v.w * wc[(DD+j+3)*2+1];
        }
        MS(tid, 0) = a0; MS(tid, 1) = a1; MS(tid, 2) = a2; MS(tid, 3) = a3;
    }

    // --- off (threads 0..3) ---
    if (tid < 4) {
        const int c = tid & 1;
        const int base = (tid < 2) ? 0 : DD;
        float o = 0.f;
        for (int j = 0; j < DIN; ++j) o += b_enc[j] * wc[(base + j) * 2 + c];
        if (tid < 2) o += b_cls[tid];     // fold b_cls into the A half
        offs[tid] = o;
    }
    __syncthreads();

    // --- cooperative per-node projection: 8 threads per node ---
    const int gid  = blockIdx.x * 256 + tid;
    const int n    = gid >> 3;            // 0..8191
    const int part = gid & 7;             // 32-dim slice
    float a0 = 0.f, a1 = 0.f, a2 = 0.f, a3 = 0.f;
    const float4* row = (const float4*)(nodes + (long long)n * DIN + part * 32);
    #pragma unroll
    for (int i = 0; i < 8; ++i) {
        const float4 v = row[i];
        const int j = part * 32 + i * 4;
        a0 += v.x * MS(j+0,0) + v.y * MS(j+1,0) + v.z * MS(j+2,0) + v.w * MS(j+3,0);
        a1 += v.x * MS(j+0,1) + v.y * MS(j+1,1) + v.z * MS(j+2,1) + v.w * MS(j+3,1);
        a2 += v.x * MS(j+0,2) + v.y * MS(j+1,2) + v.z * MS(j+2,2) + v.w * MS(j+3,2);
        a3 += v.x * MS(j+0,3) + v.y * MS(j+1,3) + v.z * MS(j+2,3) + v.w * MS(j+3,3);
    }
    #pragma unroll
    for (int d = 1; d < 8; d <<= 1) {
        a0 += __shfl_xor(a0, d);
        a1 += __shfl_xor(a1, d);
        a2 += __shfl_xor(a2, d);
        a3 += __shfl_xor(a3, d);
    }
    if (part == 0) {
        Axy[n] = make_float2(a0 + offs[0], a1 + offs[1]);
        Bzw[n] = make_float2(a2 + offs[2], a3 + offs[3]);
    }
}

// ---------------------------------------------------------------------------
// Kernel 2: fill y via triangle row-folding.  Fold `by` pairs row s1=by with
// row s2=8190-by: len(s1)+len(s2) = 8192 pairs exactly.  grid=(32, 4096),
// 1 pair/thread, one lane-contiguous fx2 NT store.  No sqrt; s,t from ~10
// int ops.  b-loads are consecutive-t (8 B/lane contiguous = 8 lines/wave);
// a-load is row-uniform.  Self-fold (by=4095) guarded.
// ---------------------------------------------------------------------------
__global__ __launch_bounds__(256) void fill_kernel(
    const float2* __restrict__ Axy,    // [8192]
    const float2* __restrict__ Bzw,    // [8192]
    float* __restrict__ y)             // [P][2]
{
    const unsigned by    = blockIdx.y;                      // fold 0..4095
    const unsigned local = blockIdx.x * 256u + threadIdx.x; // 0..8191 within fold
    const unsigned L1    = 8191u - by;                      // len of row by
    if (by == 4095u && local >= 4096u) return;              // self-fold half

    const bool     second = (local >= L1);
    const unsigned s      = second ? (8190u - by) : by;
    const unsigned tloc   = second ? (local - L1) : local;
    const unsigned rs     = (s * (16383u - s)) >> 1;        // row start s*(2N-1-s)/2
    const unsigned p      = rs + tloc;

    const float2 a = Axy[s];
    const float2 b = Bzw[s + 1u + tloc];
    fx2 v = {a.x + b.x, a.y + b.y};
    __builtin_nontemporal_store(v, (fx2*)(y + 2u * p));
}

// ---------------------------------------------------------------------------
// Kernel 3: zero yt.  8191 blocks * 256 threads * 4 fx4 = P floats exactly.
// ---------------------------------------------------------------------------
__global__ __launch_bounds__(256) void zero_kernel(float* __restrict__ yt)
{
    fx4* base = (fx4*)yt + (unsigned)blockIdx.x * 1024u + threadIdx.x;
    fx4 z = {0.f, 0.f, 0.f, 0.f};
    __builtin_nontemporal_store(z, base + 0 * 256);
    __builtin_nontemporal_store(z, base + 1 * 256);
    __builtin_nontemporal_store(z, base + 2 * 256);
    __builtin_nontemporal_store(z, base + 3 * 256);
}

// ---------------------------------------------------------------------------
// Kernel 4: scatter edge labels.  yt[pair_idx] = 1.0 for valid (u < v) edges.
// ---------------------------------------------------------------------------
__global__ __launch_bounds__(256) void edge_kernel(
    const int* __restrict__ edges,     // [2][E]
    float* __restrict__ yt,
    int E)
{
    const int e = blockIdx.x * 256 + threadIdx.x;
    if (e >= E) return;
    const int u = edges[e];
    const int v = edges[E + e];
    if (u < v) {
        const unsigned idx = (unsigned)u * (2u * NN - u - 1u) / 2u + (unsigned)(v - u - 1);
        yt[idx] = 1.0f;
    }
}

extern "C" void kernel_launch(void* const* d_in, const int* in_sizes, int n_in,
                              void* d_out, int out_size, void* d_ws, size_t ws_size,
                              hipStream_t stream) {
    const float* nodes = (const float*)d_in[0];
    const int*   edges = (const int*)d_in[1];
    const float* W_enc = (const float*)d_in[2];
    const float* b_enc = (const float*)d_in[3];
    const float* W_cls = (const float*)d_in[4];
    const float* b_cls = (const float*)d_in[5];
    const int E = in_sizes[1] / 2;

    float2* Axy = (float2*)d_ws;                  // 8192 float2
    float2* Bzw = Axy + 8192;                     // 8192 float2

    float* y  = (float*)d_out;                    // [P][2]
    float* yt = (float*)d_out + 2 * PP;           // [P]

    ab_kernel<<<256, 256, 0, stream>>>(nodes, W_enc, b_enc, W_cls, b_cls, Axy, Bzw);
    fill_kernel<<<dim3(32, 4096), 256, 0, stream>>>(Axy, Bzw, y);
    zero_kernel<<<8191, 256, 0, stream>>>(yt);
    edge_kernel<<<(E + 255) / 256, 256, 0, stream>>>(edges, yt, E);
}

// Round 10
// 78.941 us; speedup vs baseline: 1.3522x; 1.3396x over previous
//
#include <hip/hip_runtime.h>

// Problem constants (fixed by the reference file)
#define NN 8192
#define PPU 33550336u              // P = N(N-1)/2
static const long long PP = (long long)PPU;

typedef float __attribute__((ext_vector_type(4))) fx4;      // nontemporal-store-able

// skewed LDS index for M float4 rows (projection-phase conflict damping)
#define MSI(j) ((j) + ((j) >> 3))

// ---------------------------------------------------------------------------
// K1: blocks 0..255  -> ab projections (8 threads cooperate per node)
//     blocks 256..8446 -> zero yt (R6's exact zero body, shifted by 256)
// Disjoint outputs (ws vs yt) -> safe in one launch.
// ---------------------------------------------------------------------------
__global__ __launch_bounds__(256) void ab_zero_kernel(
    const float* __restrict__ nodes,   // [8192][256]
    const float* __restrict__ W_enc,   // [256][256]
    const float* __restrict__ b_enc,   // [256]
    const float* __restrict__ W_cls,   // [512][2]
    const float* __restrict__ b_cls,   // [2]
    float2* __restrict__ Axy,          // ws: [8192]
    float2* __restrict__ Bzw,          // ws: [8192]
    float*  __restrict__ yt)           // out: [P]
{
    const int tid = threadIdx.x;
    const int bid = blockIdx.x;

    if (bid >= 256) {
        // ---- zero yt: block covers 16 KB contiguous (R6 body) ----
        fx4* base = (fx4*)yt + (unsigned)(bid - 256) * 1024u + (unsigned)tid;
        fx4 z = {0.f, 0.f, 0.f, 0.f};
        __builtin_nontemporal_store(z, base + 0 * 256);
        __builtin_nontemporal_store(z, base + 1 * 256);
        __builtin_nontemporal_store(z, base + 2 * 256);
        __builtin_nontemporal_store(z, base + 3 * 256);
        return;
    }

    // ---- ab path ----
    __shared__ float  wc[1024];        // W_cls [512][2]
    __shared__ float4 msv[288];        // skewed M rows
    __shared__ float  offs[4];

    for (int i = tid; i < 1024; i += 256) wc[i] = W_cls[i];
    __syncthreads();

    // M row `tid` via vectorized (b128, broadcast) wc reads
    {
        const float4* wr  = (const float4*)(W_enc + tid * 256);
        const float4* wa4 = (const float4*)wc;          // A half: j-pairs
        const float4* wb4 = (const float4*)(wc + 512);  // B half: j-pairs
        float a0 = 0.f, a1 = 0.f, a2 = 0.f, a3 = 0.f;
        #pragma unroll 8
        for (int i = 0; i < 64; ++i) {
            const float4 v   = wr[i];
            const float4 A01 = wa4[2*i],   A23 = wa4[2*i+1];
            const float4 B01 = wb4[2*i],   B23 = wb4[2*i+1];
            a0 += v.x*A01.x + v.y*A01.z + v.z*A23.x + v.w*A23.z;
            a1 += v.x*A01.y + v.y*A01.w + v.z*A23.y + v.w*A23.w;
            a2 += v.x*B01.x + v.y*B01.z + v.z*B23.x + v.w*B23.z;
            a3 += v.x*B01.y + v.y*B01.w + v.z*B23.y + v.w*B23.w;
        }
        msv[MSI(tid)] = make_float4(a0, a1, a2, a3);
    }
    if (tid < 4) {
        const int c = tid & 1, base = (tid < 2) ? 0 : 256;
        float o = 0.f;
        for (int j = 0; j < 256; ++j) o += b_enc[j] * wc[(base + j) * 2 + c];
        if (tid < 2) o += b_cls[tid];      // fold b_cls into the A half
        offs[tid] = o;
    }
    __syncthreads();

    // 8 threads per node; lane part handles dims [32*part, 32*part+32)
    const int gid  = bid * 256 + tid;
    const int n    = gid >> 3;             // 0..8191
    const int part = gid & 7;
    float a0 = 0.f, a1 = 0.f, a2 = 0.f, a3 = 0.f;
    const float4* row = (const float4*)(nodes + (long long)n * 256 + part * 32);
    #pragma unroll
    for (int i = 0; i < 8; ++i) {
        const float4 v = row[i];
        const int j = part * 32 + i * 4;
        const float4 m0 = msv[MSI(j+0)];
        const float4 m1 = msv[MSI(j+1)];
        const float4 m2 = msv[MSI(j+2)];
        const float4 m3 = msv[MSI(j+3)];
        a0 += v.x*m0.x + v.y*m1.x + v.z*m2.x + v.w*m3.x;
        a1 += v.x*m0.y + v.y*m1.y + v.z*m2.y + v.w*m3.y;
        a2 += v.x*m0.z + v.y*m1.z + v.z*m2.z + v.w*m3.z;
        a3 += v.x*m0.w + v.y*m1.w + v.z*m2.w + v.w*m3.w;
    }
    #pragma unroll
    for (int d = 1; d < 8; d <<= 1) {
        a0 += __shfl_xor(a0, d);
        a1 += __shfl_xor(a1, d);
        a2 += __shfl_xor(a2, d);
        a3 += __shfl_xor(a3, d);
    }
    if (part == 0) {
        Axy[n] = make_float2(a0 + offs[0], a1 + offs[1]);
        Bzw[n] = make_float2(a2 + offs[2], a3 + offs[3]);
    }
}

// ---------------------------------------------------------------------------
// K2: fill y (R6's exact body; SoA Axy/Bzw) + edge scatter on first 256
// blocks (gid < E; E = 65536 = 256*256).  Runs after K1, so yt is zeroed.
// ---------------------------------------------------------------------------
__global__ __launch_bounds__(256) void fill_edge_kernel(
    const float2* __restrict__ Axy,    // [8192]
    const float2* __restrict__ Bzw,    // [8192]
    const int*    __restrict__ edges,  // [2][E]
    float* __restrict__ y,             // [P][2]
    float* __restrict__ yt,            // [P]
    int E)
{
    const unsigned g = blockIdx.x * 256u + threadIdx.x;

    // edge scatter (first E threads only)
    if (g < (unsigned)E) {
        const int u = edges[g];
        const int v = edges[E + g];
        if (u < v) {
            const unsigned idx = (((unsigned)u * (16383u - (unsigned)u)) >> 1)
                               + (unsigned)(v - u - 1);
            yt[idx] = 1.0f;
        }
    }

    const unsigned p0 = 2u * g;                       // < 2^26

    // invert p0 -> (s,t): s = floor((M - sqrt(M^2 - 8 p0))/2), M = 2N-1
    const unsigned M    = 16383u;
    const unsigned disc = M * M - 8u * p0;            // exact in uint32
    const float sq = sqrtf((float)disc);
    int s = (int)(((float)M - sq) * 0.5f);
    s = s < 0 ? 0 : (s > NN - 2 ? NN - 2 : s);
    unsigned rs = ((unsigned)s * (M - (unsigned)s)) >> 1;
    while (p0 < rs)                           { --s; rs -= (unsigned)(NN - 1 - s); }
    while (p0 >= rs + (unsigned)(NN - 1 - s)) { rs += (unsigned)(NN - 1 - s); ++s; }
    int t = (int)(p0 - rs) + s + 1;

    float2 a  = Axy[s];
    float2 b0 = Bzw[t];
    const float o0 = a.x + b0.x, o1 = a.y + b0.y;
    if (++t == NN) { ++s; t = s + 1; a = Axy[s]; }    // row crossing (rare)
    float2 b1 = Bzw[t];
    const float o2 = a.x + b1.x, o3 = a.y + b1.y;

    fx4 v = {o0, o1, o2, o3};
    __builtin_nontemporal_store(v, (fx4*)(y + 4u * g));
}

extern "C" void kernel_launch(void* const* d_in, const int* in_sizes, int n_in,
                              void* d_out, int out_size, void* d_ws, size_t ws_size,
                              hipStream_t stream) {
    const float* nodes = (const float*)d_in[0];
    const int*   edges = (const int*)d_in[1];
    const float* W_enc = (const float*)d_in[2];
    const float* b_enc = (const float*)d_in[3];
    const float* W_cls = (const float*)d_in[4];
    const float* b_cls = (const float*)d_in[5];
    const int E = in_sizes[1] / 2;

    float2* Axy = (float2*)d_ws;                  // 8192 float2
    float2* Bzw = Axy + 8192;                     // 8192 float2

    float* y  = (float*)d_out;                    // [P][2]
    float* yt = (float*)d_out + 2 * PP;           // [P]

    // K1: 256 ab blocks + 8191 zero blocks (P floats = 8191*1024 fx4 exactly)
    ab_zero_kernel<<<256 + 8191, 256, 0, stream>>>(
        nodes, W_enc, b_enc, W_cls, b_cls, Axy, Bzw, yt);

    // K2: P/2 threads (= 65528 * 256 exactly); first 256 blocks also edges
    fill_edge_kernel<<<(int)(PPU / 512u), 256, 0, stream>>>(
        Axy, Bzw, edges, y, yt, E);
}